// Round 5
// baseline (197.718 us; speedup 1.0000x reference)
//
#include <hip/hip_runtime.h>
#include <math.h>

#define B_  4
#define C_  64
#define H_  128
#define W_  128
#define HW_ (H_*W_)          // 16384
#define NPIX_ (B_*HW_)       // 65536
#define GROUPS_ 32

typedef __attribute__((ext_vector_type(8))) short short8;
typedef __attribute__((ext_vector_type(4))) float f32x4;

__device__ inline short f2bf_rne(float f) {
    unsigned u = __float_as_uint(f);
    unsigned r = (u + 0x7FFFu + ((u >> 16) & 1u)) >> 16;
    return (short)r;
}
__device__ inline float bf2f(short h) {
    return __uint_as_float(((unsigned)(unsigned short)h) << 16);
}

// ---------------------------------------------------------------------------
// K0: weight prep (bf16 hi/lo splits, transposed layouts for MFMA B-operands)
// ---------------------------------------------------------------------------
__global__ void k0_prep(const float* __restrict__ w_off1, const float* __restrict__ w_mask1,
                        const float* __restrict__ w_off2, const float* __restrict__ w_mask2,
                        short* __restrict__ w1_hi, short* __restrict__ w1_lo,
                        short* __restrict__ wo_hi, short* __restrict__ wo_lo,
                        short* __restrict__ wm_hi, short* __restrict__ wm_lo) {
    int i = blockIdx.x * 256 + threadIdx.x;
    if (i < 8192) {
        int co = i >> 6, ci = i & 63;
        float v = (co < 64) ? w_off1[co * 64 + ci] : w_mask1[(co - 64) * 64 + ci];
        short h = f2bf_rne(v);
        w1_hi[i] = h;
        w1_lo[i] = f2bf_rne(v - bf2f(h));
    }
    if (i < 32 * 576) {
        int cout = i / 576, r = i % 576;
        int pos = r >> 6, ci = r & 63;
        float v = (cout < 18) ? w_off2[(cout * 64 + ci) * 9 + pos] : 0.f;
        short h = f2bf_rne(v);
        wo_hi[i] = h;
        wo_lo[i] = f2bf_rne(v - bf2f(h));
    }
    if (i < 16 * 576) {
        int cout = i / 576, r = i % 576;
        int pos = r >> 6, ci = r & 63;
        float v = (cout < 9) ? w_mask2[(cout * 64 + ci) * 9 + pos] : 0.f;
        short h = f2bf_rne(v);
        wm_hi[i] = h;
        wm_lo[i] = f2bf_rne(v - bf2f(h));
    }
}

// ---------------------------------------------------------------------------
// K1: dual 1x1 conv via MFMA. 1 M-tile (16 px) per wave -> 1024 blocks =
// 16 waves/CU; nt-loop fully unrolled so weight loads hoist.
// Also emits xtb = bf16 NHWC copy of x for k3's gathers.
// ---------------------------------------------------------------------------
__global__ __launch_bounds__(256, 4) void k1_mfma(const float* __restrict__ x,
                                                  const short* __restrict__ w1_hi,
                                                  const short* __restrict__ w1_lo,
                                                  short* __restrict__ t1b,
                                                  short* __restrict__ t2b,
                                                  short* __restrict__ xtb) {
    int l   = threadIdx.x & 63;
    int wv  = threadIdx.x >> 6;
    int row = l >> 4, col = l & 15;
    int p0  = blockIdx.x * 64 + wv * 16;      // wave's pixel base (16 px)
    int b   = p0 >> 14;
    int hw  = p0 & (HW_ - 1);
    const float* xb = x + (size_t)b * C_ * HW_ + hw;

    short8 afr[2];
#pragma unroll
    for (int kb = 0; kb < 2; kb++) {
        int ci0 = kb * 32 + row * 8;          // A col k base
        float xv[8];
#pragma unroll
        for (int j = 0; j < 8; j++) xv[j] = xb[(ci0 + j) * HW_ + col];
        short8 a;
#pragma unroll
        for (int j = 0; j < 8; j++) a[j] = f2bf_rne(xv[j]);
        afr[kb] = a;
        union { short8 s; uint4 u; } cv2; cv2.s = a;
        *(uint4*)(xtb + ((size_t)(p0 + col)) * 64 + ci0) = cv2.u;
    }

#pragma unroll
    for (int nt = 0; nt < 8; nt++) {
        int co = nt * 16 + col;               // B col n
        union { uint4 u; short8 s; } cv;
        short8 bh0, bh1, bl0, bl1;
        const short* ph  = w1_hi + (size_t)co * 64 + row * 8;
        const short* pl_ = w1_lo + (size_t)co * 64 + row * 8;
        cv.u = *(const uint4*)(ph);        bh0 = cv.s;
        cv.u = *(const uint4*)(ph + 32);   bh1 = cv.s;
        cv.u = *(const uint4*)(pl_);       bl0 = cv.s;
        cv.u = *(const uint4*)(pl_ + 32);  bl1 = cv.s;
        short* tgt = (nt < 4) ? t1b : t2b;
        int c6 = co & 63;
        f32x4 acc = {0.f, 0.f, 0.f, 0.f};
        acc = __builtin_amdgcn_mfma_f32_16x16x32_bf16(afr[0], bh0, acc, 0, 0, 0);
        acc = __builtin_amdgcn_mfma_f32_16x16x32_bf16(afr[0], bl0, acc, 0, 0, 0);
        acc = __builtin_amdgcn_mfma_f32_16x16x32_bf16(afr[1], bh1, acc, 0, 0, 0);
        acc = __builtin_amdgcn_mfma_f32_16x16x32_bf16(afr[1], bl1, acc, 0, 0, 0);
#pragma unroll
        for (int r = 0; r < 4; r++) {
            int p = p0 + row * 4 + r;
            tgt[(size_t)p * 64 + c6] = f2bf_rne(acc[r]);
        }
    }
}

// ---------------------------------------------------------------------------
// K2: dual 3x3 conv via MFMA, K = 9pos x 64ci (pos-major), NHWC bf16 inputs.
// 1 M-tile per wave -> 1024 blocks = 16 waves/CU; K-loop fully unrolled so
// the 6 weight loads/iter hoist ahead of their MFMAs.
// Output row offmask[pix][32]: [0..17]=off, [18..26]=mask(sigmoid).
// ---------------------------------------------------------------------------
__global__ __launch_bounds__(256, 4) void k2_mfma(const short* __restrict__ t1b,
                                                  const short* __restrict__ t2b,
                                                  const short* __restrict__ wo_hi,
                                                  const short* __restrict__ wo_lo,
                                                  const short* __restrict__ wm_hi,
                                                  const short* __restrict__ wm_lo,
                                                  float* __restrict__ offmask) {
    int l   = threadIdx.x & 63;
    int wv  = threadIdx.x >> 6;
    int row = l >> 4, col = l & 15;
    int pb  = blockIdx.x * 64 + wv * 16;       // wave's pixel base (16 px, one row)
    int h   = (pb >> 7) & 127;
    int w0  = pb & 127;

    f32x4 aco0 = {0.f,0.f,0.f,0.f};
    f32x4 aco1 = {0.f,0.f,0.f,0.f};
    f32x4 acm  = {0.f,0.f,0.f,0.f};

#pragma unroll
    for (int kb = 0; kb < 18; kb++) {
        const int pos = kb >> 1;
        const int dy = pos / 3 - 1, dx = pos % 3 - 1;
        int ci0  = (kb & 1) * 32 + row * 8;
        int koff = pos * 64 + ci0;
        union { uint4 u; short8 s; } cv;
        short8 boh0, boh1, bol0, bol1, bmh, bml;
        cv.u = *(const uint4*)(wo_hi + (size_t)col * 576 + koff);        boh0 = cv.s;
        cv.u = *(const uint4*)(wo_hi + (size_t)(col + 16) * 576 + koff); boh1 = cv.s;
        cv.u = *(const uint4*)(wo_lo + (size_t)col * 576 + koff);        bol0 = cv.s;
        cv.u = *(const uint4*)(wo_lo + (size_t)(col + 16) * 576 + koff); bol1 = cv.s;
        cv.u = *(const uint4*)(wm_hi + (size_t)col * 576 + koff);        bmh  = cv.s;
        cv.u = *(const uint4*)(wm_lo + (size_t)col * 576 + koff);        bml  = cv.s;

        int w = w0 + col;
        bool valid = ((unsigned)(h + dy) < 128u) && ((unsigned)(w + dx) < 128u);
        int ps = pb + col + dy * 128 + dx;     // shifted global pixel
        short8 a1 = {0,0,0,0,0,0,0,0};
        short8 a2 = {0,0,0,0,0,0,0,0};
        if (valid) {
            cv.u = *(const uint4*)(t1b + (size_t)ps * 64 + ci0); a1 = cv.s;
            cv.u = *(const uint4*)(t2b + (size_t)ps * 64 + ci0); a2 = cv.s;
        }
        aco0 = __builtin_amdgcn_mfma_f32_16x16x32_bf16(a1, boh0, aco0, 0, 0, 0);
        aco0 = __builtin_amdgcn_mfma_f32_16x16x32_bf16(a1, bol0, aco0, 0, 0, 0);
        aco1 = __builtin_amdgcn_mfma_f32_16x16x32_bf16(a1, boh1, aco1, 0, 0, 0);
        aco1 = __builtin_amdgcn_mfma_f32_16x16x32_bf16(a1, bol1, aco1, 0, 0, 0);
        acm  = __builtin_amdgcn_mfma_f32_16x16x32_bf16(a2, bmh,  acm,  0, 0, 0);
        acm  = __builtin_amdgcn_mfma_f32_16x16x32_bf16(a2, bml,  acm,  0, 0, 0);
    }

#pragma unroll
    for (int r = 0; r < 4; r++) {
        int p = pb + row * 4 + r;
        float* om = offmask + (size_t)p * 32;
        om[col] = aco0[r];
        if (col < 2) om[16 + col] = aco1[r];
        if (col < 9) om[18 + col] = 1.f / (1.f + expf(-acm[r]));
    }
}

// ---------------------------------------------------------------------------
// K3: deformable bilinear gather + einsum + bias -> out_pre (NCHW).
// bf16 NHWC gathers; XCD-band swizzle (block i -> XCD i&7, XCD x owns rows
// [16x,16x+16) of every image). 4 threads/pixel, 16 channels each.
// ---------------------------------------------------------------------------
__global__ __launch_bounds__(256) void k3_deform(const short* __restrict__ xtb,
                                                 const float* __restrict__ offmask,
                                                 const float* __restrict__ weight,
                                                 const float* __restrict__ bias,
                                                 float* __restrict__ out_pre) {
    __shared__ float wl[C_ * 9];
    __shared__ float bl[C_];
    for (int i = threadIdx.x; i < C_ * 9; i += 256) wl[i] = weight[i];
    if (threadIdx.x < C_) bl[threadIdx.x] = bias[threadIdx.x];
    __syncthreads();

    int blk   = blockIdx.x;              // 1024 blocks, 64 pixels each
    int xcd   = blk & 7;
    int slot  = blk >> 3;                // 0..127
    int b     = slot >> 5;               // image
    int r     = (slot & 31) >> 1;        // row within band
    int hrow  = slot & 1;                // half-row
    int h     = xcd * 16 + r;
    int pl    = threadIdx.x >> 2;        // 0..63
    int chunk = threadIdx.x & 3;
    int c0    = chunk * 16;
    int w     = hrow * 64 + pl;
    int hw    = h * W_ + w;
    int P     = b * HW_ + hw;

    float acc[16];
#pragma unroll
    for (int i = 0; i < 16; i++) acc[i] = 0.f;

    const float* po = offmask + (size_t)P * 32;
    const short* xb = xtb + (size_t)b * HW_ * 64;

    for (int k = 0; k < 9; k++) {
        float offy = po[2 * k];
        float offx = po[2 * k + 1];
        float mk   = po[18 + k];
        float py = offy + (float)h + (float)(k / 3 - 1);
        float px = offx + (float)w + (float)(k % 3 - 1);
        float y0f = floorf(py), x0f = floorf(px);
        int y0 = (int)y0f, x0 = (int)x0f;
        int y1 = y0 + 1,   x1 = x0 + 1;
        float wy1 = py - y0f, wx1 = px - x0f;
        float wy0 = 1.f - wy1, wx0 = 1.f - wx1;
        bool vy0 = ((unsigned)y0 < (unsigned)H_);
        bool vy1 = ((unsigned)y1 < (unsigned)H_);
        bool vx0 = ((unsigned)x0 < (unsigned)W_);
        bool vx1 = ((unsigned)x1 < (unsigned)W_);
        int cy0 = min(max(y0, 0), H_ - 1);
        int cy1 = min(max(y1, 0), H_ - 1);
        int cx0 = min(max(x0, 0), W_ - 1);
        int cx1 = min(max(x1, 0), W_ - 1);
        float b00 = wy0 * wx0 * ((vy0 && vx0) ? mk : 0.f);
        float b01 = wy0 * wx1 * ((vy0 && vx1) ? mk : 0.f);
        float b10 = wy1 * wx0 * ((vy1 && vx0) ? mk : 0.f);
        float b11 = wy1 * wx1 * ((vy1 && vx1) ? mk : 0.f);

        const short* p00 = xb + ((size_t)cy0 * W_ + cx0) * 64 + c0;
        const short* p01 = xb + ((size_t)cy0 * W_ + cx1) * 64 + c0;
        const short* p10 = xb + ((size_t)cy1 * W_ + cx0) * 64 + c0;
        const short* p11 = xb + ((size_t)cy1 * W_ + cx1) * 64 + c0;

#pragma unroll
        for (int half = 0; half < 2; half++) {
            uint4 u00 = *(const uint4*)(p00 + 8 * half);
            uint4 u01 = *(const uint4*)(p01 + 8 * half);
            uint4 u10 = *(const uint4*)(p10 + 8 * half);
            uint4 u11 = *(const uint4*)(p11 + 8 * half);
            unsigned a00[4] = {u00.x, u00.y, u00.z, u00.w};
            unsigned a01[4] = {u01.x, u01.y, u01.z, u01.w};
            unsigned a10[4] = {u10.x, u10.y, u10.z, u10.w};
            unsigned a11[4] = {u11.x, u11.y, u11.z, u11.w};
#pragma unroll
            for (int d = 0; d < 4; d++) {
                float s_lo = b00 * __uint_as_float(a00[d] << 16)
                           + b01 * __uint_as_float(a01[d] << 16)
                           + b10 * __uint_as_float(a10[d] << 16)
                           + b11 * __uint_as_float(a11[d] << 16);
                float s_hi = b00 * __uint_as_float(a00[d] & 0xFFFF0000u)
                           + b01 * __uint_as_float(a01[d] & 0xFFFF0000u)
                           + b10 * __uint_as_float(a10[d] & 0xFFFF0000u)
                           + b11 * __uint_as_float(a11[d] & 0xFFFF0000u);
                int c = 8 * half + 2 * d;
                acc[c]     += wl[(c0 + c) * 9 + k] * s_lo;
                acc[c + 1] += wl[(c0 + c + 1) * 9 + k] * s_hi;
            }
        }
    }

    float* op = out_pre + ((size_t)b * C_ + c0) * HW_ + hw;
#pragma unroll
    for (int c = 0; c < 16; c++) op[c * HW_] = acc[c] + bl[c0 + c];
}

// ---------------------------------------------------------------------------
// K4: per-(b,group) mean / rstd. One 1024-thread block per (b*32+g).
// ---------------------------------------------------------------------------
__global__ __launch_bounds__(1024) void k4_stats(const float* __restrict__ out_pre,
                                                 float* __restrict__ stats) {
    int bg = blockIdx.x;
    const float4* p = (const float4*)(out_pre + (size_t)bg * 2 * HW_);
    float s = 0.f, ss = 0.f;
    for (int i = threadIdx.x; i < 2 * HW_ / 4; i += 1024) {
        float4 v = p[i];
        s  += v.x + v.y + v.z + v.w;
        ss += v.x * v.x + v.y * v.y + v.z * v.z + v.w * v.w;
    }
#pragma unroll
    for (int m = 1; m < 64; m <<= 1) {
        s  += __shfl_xor(s, m);
        ss += __shfl_xor(ss, m);
    }
    __shared__ float ls[32];
    int lane = threadIdx.x & 63, wid = threadIdx.x >> 6;
    if (lane == 0) { ls[wid] = s; ls[16 + wid] = ss; }
    __syncthreads();
    if (threadIdx.x == 0) {
        float S = 0.f, SS = 0.f;
#pragma unroll
        for (int i = 0; i < 16; i++) { S += ls[i]; SS += ls[16 + i]; }
        const float inv = 1.f / (2.f * HW_);
        float mean = S * inv;
        float var  = SS * inv - mean * mean;
        stats[bg * 2]     = mean;
        stats[bg * 2 + 1] = rsqrtf(var + 1e-5f);
    }
}

// ---------------------------------------------------------------------------
// K5: normalize + gamma/beta + exact GELU -> d_out (float4)
// ---------------------------------------------------------------------------
__global__ __launch_bounds__(256) void k5_norm_gelu(const float* __restrict__ out_pre,
                                                    const float* __restrict__ stats,
                                                    const float* __restrict__ gamma,
                                                    const float* __restrict__ beta,
                                                    float* __restrict__ out) {
    int i = blockIdx.x * 256 + threadIdx.x;
    int e = i << 2;
    int c = (e >> 14) & (C_ - 1);
    int b = e >> 20;
    int bg = b * GROUPS_ + (c >> 1);
    float mean = stats[bg * 2];
    float rstd = stats[bg * 2 + 1];
    float ga = gamma[c] * rstd;
    float be = beta[c] - mean * ga;
    float4 v = ((const float4*)out_pre)[i];
    float4 r;
    float t;
    t = v.x * ga + be; r.x = 0.5f * t * (1.f + erff(t * 0.70710678118654752f));
    t = v.y * ga + be; r.y = 0.5f * t * (1.f + erff(t * 0.70710678118654752f));
    t = v.z * ga + be; r.z = 0.5f * t * (1.f + erff(t * 0.70710678118654752f));
    t = v.w * ga + be; r.w = 0.5f * t * (1.f + erff(t * 0.70710678118654752f));
    ((float4*)out)[i] = r;
}

// ---------------------------------------------------------------------------
extern "C" void kernel_launch(void* const* d_in, const int* in_sizes, int n_in,
                              void* d_out, int out_size, void* d_ws, size_t ws_size,
                              hipStream_t stream) {
    const float* x       = (const float*)d_in[0];
    const float* w_off1  = (const float*)d_in[1];
    const float* w_off2  = (const float*)d_in[2];
    const float* w_mask1 = (const float*)d_in[3];
    const float* w_mask2 = (const float*)d_in[4];
    const float* weight  = (const float*)d_in[5];
    const float* bias    = (const float*)d_in[6];
    const float* gamma   = (const float*)d_in[7];
    const float* beta    = (const float*)d_in[8];
    float* out = (float*)d_out;

    char* ws = (char*)d_ws;
    size_t o = 0;
    short* w1_hi = (short*)(ws + o); o += 8192 * 2;
    short* w1_lo = (short*)(ws + o); o += 8192 * 2;
    short* wo_hi = (short*)(ws + o); o += 32 * 576 * 2;
    short* wo_lo = (short*)(ws + o); o += 32 * 576 * 2;
    short* wm_hi = (short*)(ws + o); o += 16 * 576 * 2;
    short* wm_lo = (short*)(ws + o); o += 16 * 576 * 2;
    o = (o + 255) & ~(size_t)255;
    short* t1b     = (short*)(ws + o); o += (size_t)NPIX_ * 64 * 2;
    short* t2b     = (short*)(ws + o); o += (size_t)NPIX_ * 64 * 2;
    short* xtb     = (short*)(ws + o); o += (size_t)NPIX_ * 64 * 2;
    float* offmask = (float*)(ws + o); o += (size_t)NPIX_ * 32 * 4;
    float* out_pre = (float*)(ws + o); o += (size_t)NPIX_ * 64 * 4;
    float* stats   = (float*)(ws + o); o += 256 * 4;

    hipLaunchKernelGGL(k0_prep, dim3(72), dim3(256), 0, stream,
                       w_off1, w_mask1, w_off2, w_mask2,
                       w1_hi, w1_lo, wo_hi, wo_lo, wm_hi, wm_lo);
    hipLaunchKernelGGL(k1_mfma, dim3(NPIX_ / 64), dim3(256), 0, stream,
                       x, w1_hi, w1_lo, t1b, t2b, xtb);
    hipLaunchKernelGGL(k2_mfma, dim3(NPIX_ / 64), dim3(256), 0, stream,
                       t1b, t2b, wo_hi, wo_lo, wm_hi, wm_lo, offmask);
    hipLaunchKernelGGL(k3_deform, dim3(NPIX_ / 64), dim3(256), 0, stream,
                       xtb, offmask, weight, bias, out_pre);
    hipLaunchKernelGGL(k4_stats, dim3(B_ * GROUPS_), dim3(1024), 0, stream,
                       out_pre, stats);
    hipLaunchKernelGGL(k5_norm_gelu, dim3(NPIX_ * 64 / 4 / 256), dim3(256), 0, stream,
                       out_pre, stats, gamma, beta, out);
}

// Round 6
// 149.444 us; speedup vs baseline: 1.3230x; 1.3230x over previous
//
#include <hip/hip_runtime.h>
#include <math.h>

#define B_  4
#define C_  64
#define H_  128
#define W_  128
#define HW_ (H_*W_)          // 16384
#define NPIX_ (B_*HW_)       // 65536
#define GROUPS_ 32

typedef __attribute__((ext_vector_type(8))) short short8;
typedef __attribute__((ext_vector_type(4))) float f32x4;

__device__ inline short f2bf_rne(float f) {
    unsigned u = __float_as_uint(f);
    unsigned r = (u + 0x7FFFu + ((u >> 16) & 1u)) >> 16;
    return (short)r;
}
__device__ inline float bf2f(short h) {
    return __uint_as_float(((unsigned)(unsigned short)h) << 16);
}
__device__ inline short8 ld8(const short* p) {
    union { uint4 u; short8 s; } c;
    c.u = *(const uint4*)p;
    return c.s;
}

// ---------------------------------------------------------------------------
// K0: composite weight prep. off/mask = conv3x3(conv1x1(x)) is linear, so
// Wcomp[cout][pos][ci] = sum_cm W2[cout][cm][pos] * W1[cm][ci].
// couts 0-17 = off (W_off2 o W_off1), 18-26 = mask (W_mask2 o W_mask1),
// 27-31 = zero pad. Layout [32][9][64], bf16 hi/lo split.
// ---------------------------------------------------------------------------
__global__ void k0_prep(const float* __restrict__ w_off1, const float* __restrict__ w_mask1,
                        const float* __restrict__ w_off2, const float* __restrict__ w_mask2,
                        short* __restrict__ wc_hi, short* __restrict__ wc_lo) {
    int i = blockIdx.x * 256 + threadIdx.x;     // 0..18431
    if (i >= 32 * 576) return;
    int cout = i / 576;
    int r    = i % 576;
    int pos  = r >> 6, ci = r & 63;
    float s = 0.f;
    if (cout < 18) {
        for (int cm = 0; cm < 64; cm++)
            s += w_off2[(cout * 64 + cm) * 9 + pos] * w_off1[cm * 64 + ci];
    } else if (cout < 27) {
        for (int cm = 0; cm < 64; cm++)
            s += w_mask2[((cout - 18) * 64 + cm) * 9 + pos] * w_mask1[cm * 64 + ci];
    }
    short h = f2bf_rne(s);
    wc_hi[i] = h;
    wc_lo[i] = f2bf_rne(s - bf2f(h));
}

// ---------------------------------------------------------------------------
// K1: NCHW fp32 -> NHWC bf16 transpose (xtb), MFMA-fragment write pattern
// (16B per lane, 64B contiguous segments).
// ---------------------------------------------------------------------------
__global__ __launch_bounds__(256) void k1_trans(const float* __restrict__ x,
                                                short* __restrict__ xtb) {
    int l   = threadIdx.x & 63;
    int wv  = threadIdx.x >> 6;
    int row = l >> 4, col = l & 15;
    int p0  = blockIdx.x * 64 + wv * 16;
    int b   = p0 >> 14;
    int hw  = p0 & (HW_ - 1);
    const float* xb = x + (size_t)b * C_ * HW_ + hw;
#pragma unroll
    for (int kb = 0; kb < 2; kb++) {
        int ci0 = kb * 32 + row * 8;
        float xv[8];
#pragma unroll
        for (int j = 0; j < 8; j++) xv[j] = xb[(ci0 + j) * HW_ + col];
        short8 a;
#pragma unroll
        for (int j = 0; j < 8; j++) a[j] = f2bf_rne(xv[j]);
        union { short8 s; uint4 u; } cv; cv.s = a;
        *(uint4*)(xtb + ((size_t)(p0 + col)) * 64 + ci0) = cv.u;
    }
}

// ---------------------------------------------------------------------------
// K2: fused off+mask 3x3x64 conv via MFMA on composite weights.
// K = 9pos x 64ci = 576; M = pixels; N = 32 (couts; 2 N-tiles).
// Block = 4 waves x 32 px = 128 px (one image row). 512 blocks = 2 blk/CU.
// Branch-free A loads (clamped addr + cndmask zero) + explicit next-kb
// prefetch so loads pipeline ahead of MFMAs.
// Output offmask[pix][32]: [0..17]=off, [18..26]=sigmoid(mask).
// ---------------------------------------------------------------------------
__global__ __launch_bounds__(256, 2) void k2_mfma(const short* __restrict__ xtb,
                                                  const short* __restrict__ wc_hi,
                                                  const short* __restrict__ wc_lo,
                                                  float* __restrict__ offmask) {
    int l   = threadIdx.x & 63;
    int wv  = threadIdx.x >> 6;
    int row = l >> 4, col = l & 15;
    int blk = blockIdx.x;
    int h   = blk & 127;
    int pb  = blk * 128 + wv * 32;            // wave's 32-px base
    int w0  = (pb & 127);                     // w of pixel 0 of this wave

    const short8 zero = {0,0,0,0,0,0,0,0};
    f32x4 a00 = {0.f,0.f,0.f,0.f};            // mt0, nt0
    f32x4 a01 = {0.f,0.f,0.f,0.f};            // mt0, nt1
    f32x4 a10 = {0.f,0.f,0.f,0.f};            // mt1, nt0
    f32x4 a11 = {0.f,0.f,0.f,0.f};            // mt1, nt1

    // --- prefetch kb=0 ---
    short8 cw0, cw1, cw2, cw3, ca0, ca1;
    {
        const int kb = 0, pos = 0, dy = -1, dx = -1;
        int ci0 = (kb & 1) * 32 + row * 8;
        int ko  = pos * 64 + ci0;
        cw0 = ld8(wc_hi + (size_t)col * 576 + ko);
        cw1 = ld8(wc_lo + (size_t)col * 576 + ko);
        cw2 = ld8(wc_hi + (size_t)(col + 16) * 576 + ko);
        cw3 = ld8(wc_lo + (size_t)(col + 16) * 576 + ko);
#pragma unroll
        for (int mt = 0; mt < 2; mt++) {
            int pbase = pb + mt * 16 + col;
            int w = w0 + mt * 16 + col;
            bool valid = ((unsigned)(h + dy) < 128u) && ((unsigned)(w + dx) < 128u);
            int addr = valid ? (pbase + dy * 128 + dx) : pbase;
            short8 v = ld8(xtb + (size_t)addr * 64 + ci0);
            if (mt == 0) ca0 = valid ? v : zero; else ca1 = valid ? v : zero;
        }
    }

#pragma unroll
    for (int kb = 0; kb < 18; kb++) {
        short8 nw0, nw1, nw2, nw3, na0, na1;
        if (kb < 17) {
            const int kn = kb + 1;
            const int pos = kn >> 1;
            const int dy = pos / 3 - 1, dx = pos % 3 - 1;
            int ci0 = (kn & 1) * 32 + row * 8;
            int ko  = pos * 64 + ci0;
            nw0 = ld8(wc_hi + (size_t)col * 576 + ko);
            nw1 = ld8(wc_lo + (size_t)col * 576 + ko);
            nw2 = ld8(wc_hi + (size_t)(col + 16) * 576 + ko);
            nw3 = ld8(wc_lo + (size_t)(col + 16) * 576 + ko);
#pragma unroll
            for (int mt = 0; mt < 2; mt++) {
                int pbase = pb + mt * 16 + col;
                int w = w0 + mt * 16 + col;
                bool valid = ((unsigned)(h + dy) < 128u) && ((unsigned)(w + dx) < 128u);
                int addr = valid ? (pbase + dy * 128 + dx) : pbase;
                short8 v = ld8(xtb + (size_t)addr * 64 + ci0);
                if (mt == 0) na0 = valid ? v : zero; else na1 = valid ? v : zero;
            }
        }
        a00 = __builtin_amdgcn_mfma_f32_16x16x32_bf16(ca0, cw0, a00, 0, 0, 0);
        a00 = __builtin_amdgcn_mfma_f32_16x16x32_bf16(ca0, cw1, a00, 0, 0, 0);
        a01 = __builtin_amdgcn_mfma_f32_16x16x32_bf16(ca0, cw2, a01, 0, 0, 0);
        a01 = __builtin_amdgcn_mfma_f32_16x16x32_bf16(ca0, cw3, a01, 0, 0, 0);
        a10 = __builtin_amdgcn_mfma_f32_16x16x32_bf16(ca1, cw0, a10, 0, 0, 0);
        a10 = __builtin_amdgcn_mfma_f32_16x16x32_bf16(ca1, cw1, a10, 0, 0, 0);
        a11 = __builtin_amdgcn_mfma_f32_16x16x32_bf16(ca1, cw2, a11, 0, 0, 0);
        a11 = __builtin_amdgcn_mfma_f32_16x16x32_bf16(ca1, cw3, a11, 0, 0, 0);
        cw0 = nw0; cw1 = nw1; cw2 = nw2; cw3 = nw3;
        ca0 = na0; ca1 = na1;
    }

#pragma unroll
    for (int mt = 0; mt < 2; mt++) {
        f32x4 n0 = mt ? a10 : a00;
        f32x4 n1 = mt ? a11 : a01;
#pragma unroll
        for (int r = 0; r < 4; r++) {
            int p = pb + mt * 16 + row * 4 + r;
            float* om = offmask + (size_t)p * 32;
            om[col] = n0[r];
            if (col < 2)       om[16 + col] = n1[r];
            else if (col < 11) om[16 + col] = 1.f / (1.f + expf(-n1[r]));
        }
    }
}

// ---------------------------------------------------------------------------
// K3: deformable bilinear gather + einsum + bias -> out_pre (NCHW).
// bf16 NHWC gathers; XCD-band swizzle (block i -> XCD i&7, XCD x owns rows
// [16x,16x+16) of every image). 4 threads/pixel, 16 channels each.
// ---------------------------------------------------------------------------
__global__ __launch_bounds__(256) void k3_deform(const short* __restrict__ xtb,
                                                 const float* __restrict__ offmask,
                                                 const float* __restrict__ weight,
                                                 const float* __restrict__ bias,
                                                 float* __restrict__ out_pre) {
    __shared__ float wl[C_ * 9];
    __shared__ float bl[C_];
    for (int i = threadIdx.x; i < C_ * 9; i += 256) wl[i] = weight[i];
    if (threadIdx.x < C_) bl[threadIdx.x] = bias[threadIdx.x];
    __syncthreads();

    int blk   = blockIdx.x;              // 1024 blocks, 64 pixels each
    int xcd   = blk & 7;
    int slot  = blk >> 3;                // 0..127
    int b     = slot >> 5;               // image
    int r     = (slot & 31) >> 1;        // row within band
    int hrow  = slot & 1;                // half-row
    int h     = xcd * 16 + r;
    int pl    = threadIdx.x >> 2;        // 0..63
    int chunk = threadIdx.x & 3;
    int c0    = chunk * 16;
    int w     = hrow * 64 + pl;
    int hw    = h * W_ + w;
    int P     = b * HW_ + hw;

    float acc[16];
#pragma unroll
    for (int i = 0; i < 16; i++) acc[i] = 0.f;

    const float* po = offmask + (size_t)P * 32;
    const short* xb = xtb + (size_t)b * HW_ * 64;

    for (int k = 0; k < 9; k++) {
        float offy = po[2 * k];
        float offx = po[2 * k + 1];
        float mk   = po[18 + k];
        float py = offy + (float)h + (float)(k / 3 - 1);
        float px = offx + (float)w + (float)(k % 3 - 1);
        float y0f = floorf(py), x0f = floorf(px);
        int y0 = (int)y0f, x0 = (int)x0f;
        int y1 = y0 + 1,   x1 = x0 + 1;
        float wy1 = py - y0f, wx1 = px - x0f;
        float wy0 = 1.f - wy1, wx0 = 1.f - wx1;
        bool vy0 = ((unsigned)y0 < (unsigned)H_);
        bool vy1 = ((unsigned)y1 < (unsigned)H_);
        bool vx0 = ((unsigned)x0 < (unsigned)W_);
        bool vx1 = ((unsigned)x1 < (unsigned)W_);
        int cy0 = min(max(y0, 0), H_ - 1);
        int cy1 = min(max(y1, 0), H_ - 1);
        int cx0 = min(max(x0, 0), W_ - 1);
        int cx1 = min(max(x1, 0), W_ - 1);
        float b00 = wy0 * wx0 * ((vy0 && vx0) ? mk : 0.f);
        float b01 = wy0 * wx1 * ((vy0 && vx1) ? mk : 0.f);
        float b10 = wy1 * wx0 * ((vy1 && vx0) ? mk : 0.f);
        float b11 = wy1 * wx1 * ((vy1 && vx1) ? mk : 0.f);

        const short* p00 = xb + ((size_t)cy0 * W_ + cx0) * 64 + c0;
        const short* p01 = xb + ((size_t)cy0 * W_ + cx1) * 64 + c0;
        const short* p10 = xb + ((size_t)cy1 * W_ + cx0) * 64 + c0;
        const short* p11 = xb + ((size_t)cy1 * W_ + cx1) * 64 + c0;

#pragma unroll
        for (int half = 0; half < 2; half++) {
            uint4 u00 = *(const uint4*)(p00 + 8 * half);
            uint4 u01 = *(const uint4*)(p01 + 8 * half);
            uint4 u10 = *(const uint4*)(p10 + 8 * half);
            uint4 u11 = *(const uint4*)(p11 + 8 * half);
            unsigned a00[4] = {u00.x, u00.y, u00.z, u00.w};
            unsigned a01[4] = {u01.x, u01.y, u01.z, u01.w};
            unsigned a10[4] = {u10.x, u10.y, u10.z, u10.w};
            unsigned a11[4] = {u11.x, u11.y, u11.z, u11.w};
#pragma unroll
            for (int d = 0; d < 4; d++) {
                float s_lo = b00 * __uint_as_float(a00[d] << 16)
                           + b01 * __uint_as_float(a01[d] << 16)
                           + b10 * __uint_as_float(a10[d] << 16)
                           + b11 * __uint_as_float(a11[d] << 16);
                float s_hi = b00 * __uint_as_float(a00[d] & 0xFFFF0000u)
                           + b01 * __uint_as_float(a01[d] & 0xFFFF0000u)
                           + b10 * __uint_as_float(a10[d] & 0xFFFF0000u)
                           + b11 * __uint_as_float(a11[d] & 0xFFFF0000u);
                int c = 8 * half + 2 * d;
                acc[c]     += wl[(c0 + c) * 9 + k] * s_lo;
                acc[c + 1] += wl[(c0 + c + 1) * 9 + k] * s_hi;
            }
        }
    }

    float* op = out_pre + ((size_t)b * C_ + c0) * HW_ + hw;
#pragma unroll
    for (int c = 0; c < 16; c++) op[c * HW_] = acc[c] + bl[c0 + c];
}

// ---------------------------------------------------------------------------
// K4: per-(b,group) mean / rstd. One 1024-thread block per (b*32+g).
// ---------------------------------------------------------------------------
__global__ __launch_bounds__(1024) void k4_stats(const float* __restrict__ out_pre,
                                                 float* __restrict__ stats) {
    int bg = blockIdx.x;
    const float4* p = (const float4*)(out_pre + (size_t)bg * 2 * HW_);
    float s = 0.f, ss = 0.f;
    for (int i = threadIdx.x; i < 2 * HW_ / 4; i += 1024) {
        float4 v = p[i];
        s  += v.x + v.y + v.z + v.w;
        ss += v.x * v.x + v.y * v.y + v.z * v.z + v.w * v.w;
    }
#pragma unroll
    for (int m = 1; m < 64; m <<= 1) {
        s  += __shfl_xor(s, m);
        ss += __shfl_xor(ss, m);
    }
    __shared__ float ls[32];
    int lane = threadIdx.x & 63, wid = threadIdx.x >> 6;
    if (lane == 0) { ls[wid] = s; ls[16 + wid] = ss; }
    __syncthreads();
    if (threadIdx.x == 0) {
        float S = 0.f, SS = 0.f;
#pragma unroll
        for (int i = 0; i < 16; i++) { S += ls[i]; SS += ls[16 + i]; }
        const float inv = 1.f / (2.f * HW_);
        float mean = S * inv;
        float var  = SS * inv - mean * mean;
        stats[bg * 2]     = mean;
        stats[bg * 2 + 1] = rsqrtf(var + 1e-5f);
    }
}

// ---------------------------------------------------------------------------
// K5: normalize + gamma/beta + exact GELU -> d_out (float4)
// ---------------------------------------------------------------------------
__global__ __launch_bounds__(256) void k5_norm_gelu(const float* __restrict__ out_pre,
                                                    const float* __restrict__ stats,
                                                    const float* __restrict__ gamma,
                                                    const float* __restrict__ beta,
                                                    float* __restrict__ out) {
    int i = blockIdx.x * 256 + threadIdx.x;
    int e = i << 2;
    int c = (e >> 14) & (C_ - 1);
    int b = e >> 20;
    int bg = b * GROUPS_ + (c >> 1);
    float mean = stats[bg * 2];
    float rstd = stats[bg * 2 + 1];
    float ga = gamma[c] * rstd;
    float be = beta[c] - mean * ga;
    float4 v = ((const float4*)out_pre)[i];
    float4 r;
    float t;
    t = v.x * ga + be; r.x = 0.5f * t * (1.f + erff(t * 0.70710678118654752f));
    t = v.y * ga + be; r.y = 0.5f * t * (1.f + erff(t * 0.70710678118654752f));
    t = v.z * ga + be; r.z = 0.5f * t * (1.f + erff(t * 0.70710678118654752f));
    t = v.w * ga + be; r.w = 0.5f * t * (1.f + erff(t * 0.70710678118654752f));
    ((float4*)out)[i] = r;
}

// ---------------------------------------------------------------------------
extern "C" void kernel_launch(void* const* d_in, const int* in_sizes, int n_in,
                              void* d_out, int out_size, void* d_ws, size_t ws_size,
                              hipStream_t stream) {
    const float* x       = (const float*)d_in[0];
    const float* w_off1  = (const float*)d_in[1];
    const float* w_off2  = (const float*)d_in[2];
    const float* w_mask1 = (const float*)d_in[3];
    const float* w_mask2 = (const float*)d_in[4];
    const float* weight  = (const float*)d_in[5];
    const float* bias    = (const float*)d_in[6];
    const float* gamma   = (const float*)d_in[7];
    const float* beta    = (const float*)d_in[8];
    float* out = (float*)d_out;

    char* ws = (char*)d_ws;
    size_t o = 0;
    short* wc_hi = (short*)(ws + o); o += 32 * 576 * 2;
    short* wc_lo = (short*)(ws + o); o += 32 * 576 * 2;
    o = (o + 255) & ~(size_t)255;
    short* xtb     = (short*)(ws + o); o += (size_t)NPIX_ * 64 * 2;
    float* offmask = (float*)(ws + o); o += (size_t)NPIX_ * 32 * 4;
    float* out_pre = (float*)(ws + o); o += (size_t)NPIX_ * 64 * 4;
    float* stats   = (float*)(ws + o); o += 256 * 4;

    hipLaunchKernelGGL(k0_prep, dim3(72), dim3(256), 0, stream,
                       w_off1, w_mask1, w_off2, w_mask2, wc_hi, wc_lo);
    hipLaunchKernelGGL(k1_trans, dim3(NPIX_ / 64), dim3(256), 0, stream,
                       x, xtb);
    hipLaunchKernelGGL(k2_mfma, dim3(NPIX_ / 128), dim3(256), 0, stream,
                       xtb, wc_hi, wc_lo, offmask);
    hipLaunchKernelGGL(k3_deform, dim3(NPIX_ / 64), dim3(256), 0, stream,
                       xtb, offmask, weight, bias, out_pre);
    hipLaunchKernelGGL(k4_stats, dim3(B_ * GROUPS_), dim3(1024), 0, stream,
                       out_pre, stats);
    hipLaunchKernelGGL(k5_norm_gelu, dim3(NPIX_ * 64 / 4 / 256), dim3(256), 0, stream,
                       out_pre, stats, gamma, beta, out);
}

// Round 7
// 145.999 us; speedup vs baseline: 1.3542x; 1.0236x over previous
//
#include <hip/hip_runtime.h>
#include <math.h>

#define B_  4
#define C_  64
#define H_  128
#define W_  128
#define HW_ (H_*W_)          // 16384
#define NPIX_ (B_*HW_)       // 65536
#define GROUPS_ 32

typedef __attribute__((ext_vector_type(8))) short short8;
typedef __attribute__((ext_vector_type(4))) float f32x4;

__device__ inline short f2bf_rne(float f) {
    unsigned u = __float_as_uint(f);
    unsigned r = (u + 0x7FFFu + ((u >> 16) & 1u)) >> 16;
    return (short)r;
}
__device__ inline float bf2f(short h) {
    return __uint_as_float(((unsigned)(unsigned short)h) << 16);
}
__device__ inline short8 ld8(const short* p) {
    union { uint4 u; short8 s; } c;
    c.u = *(const uint4*)p;
    return c.s;
}

// ---------------------------------------------------------------------------
// K0: composite weight prep. off/mask = conv3x3(conv1x1(x)) is linear, so
// Wcomp[cout][pos][ci] = sum_cm W2[cout][cm][pos] * W1[cm][ci].
// couts 0-17 = off, 18-26 = mask, 27-31 = zero. [32][9][64], bf16 hi/lo.
// ---------------------------------------------------------------------------
__global__ void k0_prep(const float* __restrict__ w_off1, const float* __restrict__ w_mask1,
                        const float* __restrict__ w_off2, const float* __restrict__ w_mask2,
                        short* __restrict__ wc_hi, short* __restrict__ wc_lo) {
    int i = blockIdx.x * 256 + threadIdx.x;     // 0..18431
    if (i >= 32 * 576) return;
    int cout = i / 576;
    int r    = i % 576;
    int pos  = r >> 6, ci = r & 63;
    float s = 0.f;
    if (cout < 18) {
        for (int cm = 0; cm < 64; cm++)
            s += w_off2[(cout * 64 + cm) * 9 + pos] * w_off1[cm * 64 + ci];
    } else if (cout < 27) {
        for (int cm = 0; cm < 64; cm++)
            s += w_mask2[((cout - 18) * 64 + cm) * 9 + pos] * w_mask1[cm * 64 + ci];
    }
    short h = f2bf_rne(s);
    wc_hi[i] = h;
    wc_lo[i] = f2bf_rne(s - bf2f(h));
}

// ---------------------------------------------------------------------------
// K1: NCHW fp32 -> NHWC bf16 transpose (xtb), MFMA-fragment write pattern.
// ---------------------------------------------------------------------------
__global__ __launch_bounds__(256) void k1_trans(const float* __restrict__ x,
                                                short* __restrict__ xtb) {
    int l   = threadIdx.x & 63;
    int wv  = threadIdx.x >> 6;
    int row = l >> 4, col = l & 15;
    int p0  = blockIdx.x * 64 + wv * 16;
    int b   = p0 >> 14;
    int hw  = p0 & (HW_ - 1);
    const float* xb = x + (size_t)b * C_ * HW_ + hw;
#pragma unroll
    for (int kb = 0; kb < 2; kb++) {
        int ci0 = kb * 32 + row * 8;
        float xv[8];
#pragma unroll
        for (int j = 0; j < 8; j++) xv[j] = xb[(ci0 + j) * HW_ + col];
        short8 a;
#pragma unroll
        for (int j = 0; j < 8; j++) a[j] = f2bf_rne(xv[j]);
        union { short8 s; uint4 u; } cv; cv.s = a;
        *(uint4*)(xtb + ((size_t)(p0 + col)) * 64 + ci0) = cv.u;
    }
}

// ---------------------------------------------------------------------------
// K2: fused off+mask 3x3x64 conv via MFMA on composite weights.
// K=576, N=32 (2 N-tiles), block = 4 waves x 32 px = one image row.
// Branch-free pipelined A loads. offmask[pix][32]: [0..17]=off, [18..26]=sig.
// ---------------------------------------------------------------------------
__global__ __launch_bounds__(256, 2) void k2_mfma(const short* __restrict__ xtb,
                                                  const short* __restrict__ wc_hi,
                                                  const short* __restrict__ wc_lo,
                                                  float* __restrict__ offmask) {
    int l   = threadIdx.x & 63;
    int wv  = threadIdx.x >> 6;
    int row = l >> 4, col = l & 15;
    int blk = blockIdx.x;
    int h   = blk & 127;
    int pb  = blk * 128 + wv * 32;            // wave's 32-px base
    int w0  = (pb & 127);

    const short8 zero = {0,0,0,0,0,0,0,0};
    f32x4 a00 = {0.f,0.f,0.f,0.f};
    f32x4 a01 = {0.f,0.f,0.f,0.f};
    f32x4 a10 = {0.f,0.f,0.f,0.f};
    f32x4 a11 = {0.f,0.f,0.f,0.f};

    short8 cw0, cw1, cw2, cw3, ca0, ca1;
    {
        const int pos = 0, dy = -1, dx = -1;
        int ci0 = row * 8;
        int ko  = pos * 64 + ci0;
        cw0 = ld8(wc_hi + (size_t)col * 576 + ko);
        cw1 = ld8(wc_lo + (size_t)col * 576 + ko);
        cw2 = ld8(wc_hi + (size_t)(col + 16) * 576 + ko);
        cw3 = ld8(wc_lo + (size_t)(col + 16) * 576 + ko);
#pragma unroll
        for (int mt = 0; mt < 2; mt++) {
            int pbase = pb + mt * 16 + col;
            int w = w0 + mt * 16 + col;
            bool valid = ((unsigned)(h + dy) < 128u) && ((unsigned)(w + dx) < 128u);
            int addr = valid ? (pbase + dy * 128 + dx) : pbase;
            short8 v = ld8(xtb + (size_t)addr * 64 + ci0);
            if (mt == 0) ca0 = valid ? v : zero; else ca1 = valid ? v : zero;
        }
    }

#pragma unroll
    for (int kb = 0; kb < 18; kb++) {
        short8 nw0, nw1, nw2, nw3, na0, na1;
        if (kb < 17) {
            const int kn = kb + 1;
            const int pos = kn >> 1;
            const int dy = pos / 3 - 1, dx = pos % 3 - 1;
            int ci0 = (kn & 1) * 32 + row * 8;
            int ko  = pos * 64 + ci0;
            nw0 = ld8(wc_hi + (size_t)col * 576 + ko);
            nw1 = ld8(wc_lo + (size_t)col * 576 + ko);
            nw2 = ld8(wc_hi + (size_t)(col + 16) * 576 + ko);
            nw3 = ld8(wc_lo + (size_t)(col + 16) * 576 + ko);
#pragma unroll
            for (int mt = 0; mt < 2; mt++) {
                int pbase = pb + mt * 16 + col;
                int w = w0 + mt * 16 + col;
                bool valid = ((unsigned)(h + dy) < 128u) && ((unsigned)(w + dx) < 128u);
                int addr = valid ? (pbase + dy * 128 + dx) : pbase;
                short8 v = ld8(xtb + (size_t)addr * 64 + ci0);
                if (mt == 0) na0 = valid ? v : zero; else na1 = valid ? v : zero;
            }
        }
        a00 = __builtin_amdgcn_mfma_f32_16x16x32_bf16(ca0, cw0, a00, 0, 0, 0);
        a00 = __builtin_amdgcn_mfma_f32_16x16x32_bf16(ca0, cw1, a00, 0, 0, 0);
        a01 = __builtin_amdgcn_mfma_f32_16x16x32_bf16(ca0, cw2, a01, 0, 0, 0);
        a01 = __builtin_amdgcn_mfma_f32_16x16x32_bf16(ca0, cw3, a01, 0, 0, 0);
        a10 = __builtin_amdgcn_mfma_f32_16x16x32_bf16(ca1, cw0, a10, 0, 0, 0);
        a10 = __builtin_amdgcn_mfma_f32_16x16x32_bf16(ca1, cw1, a10, 0, 0, 0);
        a11 = __builtin_amdgcn_mfma_f32_16x16x32_bf16(ca1, cw2, a11, 0, 0, 0);
        a11 = __builtin_amdgcn_mfma_f32_16x16x32_bf16(ca1, cw3, a11, 0, 0, 0);
        cw0 = nw0; cw1 = nw1; cw2 = nw2; cw3 = nw3;
        ca0 = na0; ca1 = na1;
    }

#pragma unroll
    for (int mt = 0; mt < 2; mt++) {
        f32x4 n0 = mt ? a10 : a00;
        f32x4 n1 = mt ? a11 : a01;
#pragma unroll
        for (int r = 0; r < 4; r++) {
            int p = pb + mt * 16 + row * 4 + r;
            float* om = offmask + (size_t)p * 32;
            om[col] = n0[r];
            if (col < 2)       om[16 + col] = n1[r];
            else if (col < 11) om[16 + col] = 1.f / (1.f + expf(-n1[r]));
        }
    }
}

// ---------------------------------------------------------------------------
// K3: deformable bilinear gather + einsum + bias -> out_pre (NCHW, bf16)
// PLUS per-block GroupNorm partial sums (each block = 64 px x all 64 ch of
// one image -> partial (S,SS) for all 32 groups via shuffle+LDS).
// bf16 NHWC gathers; XCD-band swizzle. 4 threads/pixel, 16 channels each.
// ---------------------------------------------------------------------------
__global__ __launch_bounds__(256) void k3_deform(const short* __restrict__ xtb,
                                                 const float* __restrict__ offmask,
                                                 const float* __restrict__ weight,
                                                 const float* __restrict__ bias,
                                                 unsigned short* __restrict__ out_pre,
                                                 float* __restrict__ partials) {
    __shared__ float wl[C_ * 9];
    __shared__ float bl[C_];
    __shared__ float lds_s[4][4][8];
    __shared__ float lds_ss[4][4][8];
    for (int i = threadIdx.x; i < C_ * 9; i += 256) wl[i] = weight[i];
    if (threadIdx.x < C_) bl[threadIdx.x] = bias[threadIdx.x];
    __syncthreads();

    int blk   = blockIdx.x;              // 1024 blocks, 64 pixels each
    int xcd   = blk & 7;
    int slot  = blk >> 3;                // 0..127
    int b     = slot >> 5;               // image
    int r     = (slot & 31) >> 1;        // row within band
    int hrow  = slot & 1;                // half-row
    int h     = xcd * 16 + r;
    int pl    = threadIdx.x >> 2;        // 0..63
    int chunk = threadIdx.x & 3;
    int c0    = chunk * 16;
    int w     = hrow * 64 + pl;
    int hw    = h * W_ + w;
    int P     = b * HW_ + hw;
    int slot_img = xcd * 32 + (slot & 31);   // 0..255 within image

    float acc[16];
#pragma unroll
    for (int i = 0; i < 16; i++) acc[i] = 0.f;

    const float* po = offmask + (size_t)P * 32;
    const short* xb = xtb + (size_t)b * HW_ * 64;

    for (int k = 0; k < 9; k++) {
        float offy = po[2 * k];
        float offx = po[2 * k + 1];
        float mk   = po[18 + k];
        float py = offy + (float)h + (float)(k / 3 - 1);
        float px = offx + (float)w + (float)(k % 3 - 1);
        float y0f = floorf(py), x0f = floorf(px);
        int y0 = (int)y0f, x0 = (int)x0f;
        int y1 = y0 + 1,   x1 = x0 + 1;
        float wy1 = py - y0f, wx1 = px - x0f;
        float wy0 = 1.f - wy1, wx0 = 1.f - wx1;
        bool vy0 = ((unsigned)y0 < (unsigned)H_);
        bool vy1 = ((unsigned)y1 < (unsigned)H_);
        bool vx0 = ((unsigned)x0 < (unsigned)W_);
        bool vx1 = ((unsigned)x1 < (unsigned)W_);
        int cy0 = min(max(y0, 0), H_ - 1);
        int cy1 = min(max(y1, 0), H_ - 1);
        int cx0 = min(max(x0, 0), W_ - 1);
        int cx1 = min(max(x1, 0), W_ - 1);
        float b00 = wy0 * wx0 * ((vy0 && vx0) ? mk : 0.f);
        float b01 = wy0 * wx1 * ((vy0 && vx1) ? mk : 0.f);
        float b10 = wy1 * wx0 * ((vy1 && vx0) ? mk : 0.f);
        float b11 = wy1 * wx1 * ((vy1 && vx1) ? mk : 0.f);

        const short* p00 = xb + ((size_t)cy0 * W_ + cx0) * 64 + c0;
        const short* p01 = xb + ((size_t)cy0 * W_ + cx1) * 64 + c0;
        const short* p10 = xb + ((size_t)cy1 * W_ + cx0) * 64 + c0;
        const short* p11 = xb + ((size_t)cy1 * W_ + cx1) * 64 + c0;

#pragma unroll
        for (int half = 0; half < 2; half++) {
            uint4 u00 = *(const uint4*)(p00 + 8 * half);
            uint4 u01 = *(const uint4*)(p01 + 8 * half);
            uint4 u10 = *(const uint4*)(p10 + 8 * half);
            uint4 u11 = *(const uint4*)(p11 + 8 * half);
            unsigned a00[4] = {u00.x, u00.y, u00.z, u00.w};
            unsigned a01[4] = {u01.x, u01.y, u01.z, u01.w};
            unsigned a10[4] = {u10.x, u10.y, u10.z, u10.w};
            unsigned a11[4] = {u11.x, u11.y, u11.z, u11.w};
#pragma unroll
            for (int d = 0; d < 4; d++) {
                float s_lo = b00 * __uint_as_float(a00[d] << 16)
                           + b01 * __uint_as_float(a01[d] << 16)
                           + b10 * __uint_as_float(a10[d] << 16)
                           + b11 * __uint_as_float(a11[d] << 16);
                float s_hi = b00 * __uint_as_float(a00[d] & 0xFFFF0000u)
                           + b01 * __uint_as_float(a01[d] & 0xFFFF0000u)
                           + b10 * __uint_as_float(a10[d] & 0xFFFF0000u)
                           + b11 * __uint_as_float(a11[d] & 0xFFFF0000u);
                int c = 8 * half + 2 * d;
                acc[c]     += wl[(c0 + c) * 9 + k] * s_lo;
                acc[c + 1] += wl[(c0 + c + 1) * 9 + k] * s_hi;
            }
        }
    }

    // bias + bf16 store
    unsigned short* op = out_pre + ((size_t)b * C_ + c0) * HW_ + hw;
#pragma unroll
    for (int c = 0; c < 16; c++) {
        acc[c] += bl[c0 + c];
        op[c * HW_] = (unsigned short)f2bf_rne(acc[c]);
    }

    // GroupNorm partials: groups for this thread = chunk*8 + j, j=0..7
    float s8[8], ss8[8];
#pragma unroll
    for (int j = 0; j < 8; j++) {
        float a0 = acc[2 * j], a1 = acc[2 * j + 1];
        s8[j]  = a0 + a1;
        ss8[j] = a0 * a0 + a1 * a1;
    }
#pragma unroll
    for (int m = 4; m < 64; m <<= 1) {
#pragma unroll
        for (int j = 0; j < 8; j++) {
            s8[j]  += __shfl_xor(s8[j], m);
            ss8[j] += __shfl_xor(ss8[j], m);
        }
    }
    int lane = threadIdx.x & 63, wid = threadIdx.x >> 6;
    if (lane < 4) {
#pragma unroll
        for (int j = 0; j < 8; j++) {
            lds_s[wid][lane][j]  = s8[j];
            lds_ss[wid][lane][j] = ss8[j];
        }
    }
    __syncthreads();
    if (threadIdx.x < 32) {
        int g = threadIdx.x;
        int ch = g >> 3, j = g & 7;
        float S  = lds_s[0][ch][j] + lds_s[1][ch][j] + lds_s[2][ch][j] + lds_s[3][ch][j];
        float SS = lds_ss[0][ch][j] + lds_ss[1][ch][j] + lds_ss[2][ch][j] + lds_ss[3][ch][j];
        float2 v = make_float2(S, SS);
        *(float2*)(partials + (((size_t)(b * GROUPS_ + g)) * 256 + slot_img) * 2) = v;
    }
}

// ---------------------------------------------------------------------------
// K4: reduce partials -> stats. 128 blocks (one per b*32+g), 256 threads.
// ---------------------------------------------------------------------------
__global__ __launch_bounds__(256) void k4_reduce(const float* __restrict__ partials,
                                                 float* __restrict__ stats) {
    int bg = blockIdx.x;
    float2 v = ((const float2*)partials)[bg * 256 + threadIdx.x];
    float s = v.x, ss = v.y;
#pragma unroll
    for (int m = 1; m < 64; m <<= 1) {
        s  += __shfl_xor(s, m);
        ss += __shfl_xor(ss, m);
    }
    __shared__ float ls[8];
    int lane = threadIdx.x & 63, wid = threadIdx.x >> 6;
    if (lane == 0) { ls[wid] = s; ls[4 + wid] = ss; }
    __syncthreads();
    if (threadIdx.x == 0) {
        float S  = ls[0] + ls[1] + ls[2] + ls[3];
        float SS = ls[4] + ls[5] + ls[6] + ls[7];
        const float inv = 1.f / (2.f * HW_);
        float mean = S * inv;
        float var  = SS * inv - mean * mean;
        stats[bg * 2]     = mean;
        stats[bg * 2 + 1] = rsqrtf(var + 1e-5f);
    }
}

// ---------------------------------------------------------------------------
// K5: normalize + gamma/beta + exact GELU. Reads bf16 out_pre (8/thread),
// writes fp32 d_out.
// ---------------------------------------------------------------------------
__global__ __launch_bounds__(256) void k5_norm_gelu(const unsigned short* __restrict__ out_pre,
                                                    const float* __restrict__ stats,
                                                    const float* __restrict__ gamma,
                                                    const float* __restrict__ beta,
                                                    float* __restrict__ out) {
    int i = blockIdx.x * 256 + threadIdx.x;       // 8-element index
    int e = i << 3;
    int c = (e >> 14) & (C_ - 1);
    int b = e >> 20;
    int bg = b * GROUPS_ + (c >> 1);
    float mean = stats[bg * 2];
    float rstd = stats[bg * 2 + 1];
    float ga = gamma[c] * rstd;
    float be = beta[c] - mean * ga;
    uint4 v = ((const uint4*)out_pre)[i];
    unsigned dw[4] = {v.x, v.y, v.z, v.w};
    float4 r0, r1;
    float o[8];
#pragma unroll
    for (int d = 0; d < 4; d++) {
        float lo = __uint_as_float(dw[d] << 16);
        float hi = __uint_as_float(dw[d] & 0xFFFF0000u);
        float t0 = lo * ga + be;
        float t1 = hi * ga + be;
        o[2 * d]     = 0.5f * t0 * (1.f + erff(t0 * 0.70710678118654752f));
        o[2 * d + 1] = 0.5f * t1 * (1.f + erff(t1 * 0.70710678118654752f));
    }
    r0 = make_float4(o[0], o[1], o[2], o[3]);
    r1 = make_float4(o[4], o[5], o[6], o[7]);
    ((float4*)out)[2 * i]     = r0;
    ((float4*)out)[2 * i + 1] = r1;
}

// ---------------------------------------------------------------------------
extern "C" void kernel_launch(void* const* d_in, const int* in_sizes, int n_in,
                              void* d_out, int out_size, void* d_ws, size_t ws_size,
                              hipStream_t stream) {
    const float* x       = (const float*)d_in[0];
    const float* w_off1  = (const float*)d_in[1];
    const float* w_off2  = (const float*)d_in[2];
    const float* w_mask1 = (const float*)d_in[3];
    const float* w_mask2 = (const float*)d_in[4];
    const float* weight  = (const float*)d_in[5];
    const float* bias    = (const float*)d_in[6];
    const float* gamma   = (const float*)d_in[7];
    const float* beta    = (const float*)d_in[8];
    float* out = (float*)d_out;

    char* ws = (char*)d_ws;
    size_t o = 0;
    short* wc_hi = (short*)(ws + o); o += 32 * 576 * 2;
    short* wc_lo = (short*)(ws + o); o += 32 * 576 * 2;
    o = (o + 255) & ~(size_t)255;
    short* xtb               = (short*)(ws + o);          o += (size_t)NPIX_ * 64 * 2;
    float* offmask           = (float*)(ws + o);          o += (size_t)NPIX_ * 32 * 4;
    unsigned short* out_pre  = (unsigned short*)(ws + o); o += (size_t)NPIX_ * 64 * 2;
    float* partials          = (float*)(ws + o);          o += (size_t)128 * 256 * 2 * 4;
    float* stats             = (float*)(ws + o);          o += 256 * 4;

    hipLaunchKernelGGL(k0_prep, dim3(72), dim3(256), 0, stream,
                       w_off1, w_mask1, w_off2, w_mask2, wc_hi, wc_lo);
    hipLaunchKernelGGL(k1_trans, dim3(NPIX_ / 64), dim3(256), 0, stream,
                       x, xtb);
    hipLaunchKernelGGL(k2_mfma, dim3(NPIX_ / 128), dim3(256), 0, stream,
                       xtb, wc_hi, wc_lo, offmask);
    hipLaunchKernelGGL(k3_deform, dim3(NPIX_ / 64), dim3(256), 0, stream,
                       xtb, offmask, weight, bias, out_pre, partials);
    hipLaunchKernelGGL(k4_reduce, dim3(B_ * GROUPS_), dim3(256), 0, stream,
                       partials, stats);
    hipLaunchKernelGGL(k5_norm_gelu, dim3(NPIX_ * 64 / 8 / 256), dim3(256), 0, stream,
                       out_pre, stats, gamma, beta, out);
}